// Round 1
// baseline (3977.864 us; speedup 1.0000x reference)
//
#include <hip/hip_runtime.h>
#include <math.h>

#define THREADS 256

__device__ __forceinline__ float gelu_exact(float v) {
    return 0.5f * v * (1.0f + erff(v * 0.70710678118654752f));
}

// ---------------- Kernel 1: PropertyNormalizer (xn) ----------------
__global__ void __launch_bounds__(THREADS) xn_kernel(const float* __restrict__ x,
                                                     float* __restrict__ out, int total) {
    int i = blockIdx.x * blockDim.x + threadIdx.x;
    if (i >= total) return;
    int col = i % 35;
    float v = x[i];
    float lo = 0.f, hi = 0.f;
    bool bin = true;
    switch (col) {
        case 23: lo = -4.5f;  hi = 4.5f;   break;
        case 24: lo = -2.0f;  hi = 2.0f;   break;
        case 25: lo = 75.0f;  hi = 204.0f; break;
        case 26: lo = 60.0f;  hi = 230.0f; break;
        case 32: lo = 0.0f;   hi = 1.0f;   break;
        case 34: lo = 0.0f;   hi = 100.0f; break;
        default: bin = false; break;
    }
    if (bin) {
        float vc = fminf(fmaxf(v, lo), hi);
        float vn = (vc - lo) / (hi - lo + 1e-6f);
        v = floorf(vn * 10.0f) / 10.0f;
    }
    out[i] = v;
}

// ---------------- CSR build: histogram of dst ----------------
__global__ void __launch_bounds__(THREADS) hist_kernel(const int* __restrict__ ei,
                                                       int* __restrict__ deg, int E) {
    int e = blockIdx.x * blockDim.x + threadIdx.x;
    if (e >= E) return;
    atomicAdd(&deg[ei[E + e]], 1);  // int atomic, fire-and-forget
}

// ---------------- CSR build: two-level exclusive scan ----------------
__global__ void __launch_bounds__(THREADS) scan1_kernel(const int* __restrict__ deg,
        int* __restrict__ excl, int* __restrict__ blksum, int N) {
    __shared__ int lds[THREADS];
    int t = threadIdx.x;
    int base = blockIdx.x * 2048 + t * 8;
    int v[8];
    int s = 0;
    #pragma unroll
    for (int j = 0; j < 8; ++j) {
        int idx = base + j;
        v[j] = (idx < N) ? deg[idx] : 0;
        s += v[j];
    }
    lds[t] = s;
    __syncthreads();
    int own = s;
    for (int off = 1; off < THREADS; off <<= 1) {
        int add = (t >= off) ? lds[t - off] : 0;
        __syncthreads();
        lds[t] += add;
        __syncthreads();
    }
    int pre = lds[t] - own;  // exclusive prefix within chunk
    #pragma unroll
    for (int j = 0; j < 8; ++j) {
        int idx = base + j;
        if (idx < N) excl[idx] = pre;
        pre += v[j];
    }
    if (t == THREADS - 1) blksum[blockIdx.x] = lds[THREADS - 1];
}

__global__ void __launch_bounds__(1024) scan2_kernel(int* __restrict__ blksum, int nblk) {
    __shared__ int lds[1024];
    int t = threadIdx.x;
    int v = (t < nblk) ? blksum[t] : 0;
    lds[t] = v;
    __syncthreads();
    for (int off = 1; off < 1024; off <<= 1) {
        int add = (t >= off) ? lds[t - off] : 0;
        __syncthreads();
        lds[t] += add;
        __syncthreads();
    }
    if (t < nblk) blksum[t] = lds[t] - v;  // exclusive
}

__global__ void __launch_bounds__(THREADS) scan3_kernel(int* __restrict__ cursor,
        const int* __restrict__ blksum, int N) {
    int i = blockIdx.x * blockDim.x + threadIdx.x;
    if (i >= N) return;
    cursor[i] += blksum[i >> 11];
}

// ---------------- CSR build: scatter src ids into dst segments ----------------
__global__ void __launch_bounds__(THREADS) scatter_kernel(const int* __restrict__ ei,
        int* __restrict__ cursor, int* __restrict__ ssrc, int E) {
    int e = blockIdx.x * blockDim.x + threadIdx.x;
    if (e >= E) return;
    int s = ei[e];
    int d = ei[E + e];
    int p = atomicAdd(&cursor[d], 1);
    ssrc[p] = s;
}

// ---------------- Spatial encoder, gather form: one wave per node ----------------
__global__ void __launch_bounds__(THREADS) spatial_gather_kernel(
        const float* __restrict__ pos, const int* __restrict__ deg,
        const int* __restrict__ cursor, const int* __restrict__ ssrc,
        const float* __restrict__ w1, const float* __restrict__ b1,
        const float* __restrict__ lng, const float* __restrict__ lnb,
        const float* __restrict__ w2, const float* __restrict__ b2,
        float* __restrict__ pos_emb, int N) {
    int n = blockIdx.x * (THREADS / 64) + (threadIdx.x >> 6);
    if (n >= N) return;
    int lane = threadIdx.x & 63;
    int c = lane & 31;
    int hbase = lane & 32;  // 0 for half 0, 32 for half 1
    int half = lane >> 5;

    // hoist all channel-c weights into registers (L1-resident broadcast loads)
    float w1x = w1[c], w1y = w1[32 + c], w1z = w1[64 + c];
    float bb1 = b1[c], lg = lng[c], lb = lnb[c];
    float w2c[32];
    #pragma unroll
    for (int k = 0; k < 32; ++k) w2c[k] = w2[k * 32 + c];

    int dn = deg[n];
    int base = cursor[n] - dn;   // cursor[n] is segment end after scatter
    float px = pos[3 * n + 0], py = pos[3 * n + 1], pz = pos[3 * n + 2];

    float acc = 0.f;
    int i = half;
    int s0 = (i < dn) ? ssrc[base + i] : 0;
    float nx = pos[3 * s0 + 0], ny = pos[3 * s0 + 1], nz = pos[3 * s0 + 2];
    for (; i < dn; i += 2) {
        float rx = px - nx, ry = py - ny, rz = pz - nz;
        // software-prefetch next edge's src position
        int i2 = i + 2;
        int s2 = (i2 < dn) ? ssrc[base + i2] : s0;
        nx = pos[3 * s2 + 0]; ny = pos[3 * s2 + 1]; nz = pos[3 * s2 + 2];

        float dist = sqrtf(rx * rx + ry * ry + rz * rz);
        float inv = 1.0f / (dist + 1e-6f);
        rx *= inv; ry *= inv; rz *= inv;

        float h = bb1 + rx * w1x + ry * w1y + rz * w1z;
        // LayerNorm over 32 channels within the half-wave
        float s1 = h, sq = h * h;
        #pragma unroll
        for (int m = 1; m < 32; m <<= 1) {
            s1 += __shfl_xor(s1, m);
            sq += __shfl_xor(sq, m);
        }
        float mean = s1 * (1.0f / 32.0f);
        float var = sq * (1.0f / 32.0f) - mean * mean;
        float rstd = rsqrtf(var + 1e-5f);
        float g = gelu_exact((h - mean) * rstd * lg + lb);

        // second layer: o_c = sum_k g_k * W2[k][c]
        float o0 = 0.f, o1 = 0.f, o2 = 0.f, o3 = 0.f;
        #pragma unroll
        for (int k = 0; k < 32; k += 4) {
            o0 += __shfl(g, hbase | k)       * w2c[k];
            o1 += __shfl(g, hbase | (k + 1)) * w2c[k + 1];
            o2 += __shfl(g, hbase | (k + 2)) * w2c[k + 2];
            o3 += __shfl(g, hbase | (k + 3)) * w2c[k + 3];
        }
        acc += (o0 + o1) + (o2 + o3);
    }
    acc += __shfl_xor(acc, 32);  // combine the two halves
    if (half == 0) {
        float r = (dn > 0) ? (acc / (float)dn + b2[c]) : 0.f;
        pos_emb[(size_t)n * 32 + c] = r;
    }
}

// ---------------- Kernel 4: heterogeneous EdgeProcessor ----------------
__global__ void __launch_bounds__(THREADS) edgeproc_kernel(
        const float* __restrict__ edge_attr, const int* __restrict__ edge_type,
        const float* __restrict__ e_w, const float* __restrict__ e_b,
        const float* __restrict__ e_g, const float* __restrict__ e_lb,
        float* __restrict__ ef, int E) {
    __shared__ float sW[4096];           // [4][16][64]
    __shared__ float sB[256], sG[256], sLB[256];
    for (int i = threadIdx.x; i < 4096; i += blockDim.x) sW[i] = e_w[i];
    if (threadIdx.x < 256) {
        sB[threadIdx.x]  = e_b[threadIdx.x];
        sG[threadIdx.x]  = e_g[threadIdx.x];
        sLB[threadIdx.x] = e_lb[threadIdx.x];
    }
    __syncthreads();

    int e = (int)((blockIdx.x * (unsigned)blockDim.x + threadIdx.x) >> 6);
    int lane = threadIdx.x & 63;
    if (e >= E) return;

    int t = edge_type[e];
    const float4* xr = (const float4*)(edge_attr + (size_t)e * 16);
    float4 x0 = xr[0], x1 = xr[1], x2 = xr[2], x3 = xr[3];

    const float* W = sW + t * 1024;      // [16][64]
    float acc = sB[t * 64 + lane];
    acc += x0.x * W[0 * 64 + lane];  acc += x0.y * W[1 * 64 + lane];
    acc += x0.z * W[2 * 64 + lane];  acc += x0.w * W[3 * 64 + lane];
    acc += x1.x * W[4 * 64 + lane];  acc += x1.y * W[5 * 64 + lane];
    acc += x1.z * W[6 * 64 + lane];  acc += x1.w * W[7 * 64 + lane];
    acc += x2.x * W[8 * 64 + lane];  acc += x2.y * W[9 * 64 + lane];
    acc += x2.z * W[10 * 64 + lane]; acc += x2.w * W[11 * 64 + lane];
    acc += x3.x * W[12 * 64 + lane]; acc += x3.y * W[13 * 64 + lane];
    acc += x3.z * W[14 * 64 + lane]; acc += x3.w * W[15 * 64 + lane];

    float s1 = acc, s2 = acc * acc;
    #pragma unroll
    for (int m = 1; m < 64; m <<= 1) {
        s1 += __shfl_xor(s1, m, 64);
        s2 += __shfl_xor(s2, m, 64);
    }
    float mean = s1 * (1.0f / 64.0f);
    float var  = s2 * (1.0f / 64.0f) - mean * mean;
    float rstd = rsqrtf(var + 1e-5f);
    float ny = (acc - mean) * rstd * sG[t * 64 + lane] + sLB[t * 64 + lane];
    ef[(size_t)e * 64 + lane] = gelu_exact(ny);
}

extern "C" void kernel_launch(void* const* d_in, const int* in_sizes, int n_in,
                              void* d_out, int out_size, void* d_ws, size_t ws_size,
                              hipStream_t stream) {
    const float* x         = (const float*)d_in[0];
    const float* pos       = (const float*)d_in[1];
    const float* edge_attr = (const float*)d_in[2];
    const float* sp_w1     = (const float*)d_in[3];
    const float* sp_b1     = (const float*)d_in[4];
    const float* sp_ln_g   = (const float*)d_in[5];
    const float* sp_ln_b   = (const float*)d_in[6];
    const float* sp_w2     = (const float*)d_in[7];
    const float* sp_b2     = (const float*)d_in[8];
    const float* e_w       = (const float*)d_in[9];
    const float* e_b       = (const float*)d_in[10];
    const float* e_ln_g    = (const float*)d_in[11];
    const float* e_ln_b    = (const float*)d_in[12];
    const int*   edge_index= (const int*)d_in[13];
    const int*   edge_type = (const int*)d_in[14];

    const int N = in_sizes[0] / 35;
    const int E = in_sizes[2] / 16;

    float* out     = (float*)d_out;
    float* xn      = out;
    float* pos_emb = out + (size_t)N * 35;
    float* ef      = pos_emb + (size_t)N * 32;

    // workspace (ints): deg[N], cursor[N], blksum[1024], ssrc[E]  (~13.0 MB)
    int* deg    = (int*)d_ws;
    int* cursor = deg + N;
    int* blksum = cursor + N;
    int* ssrc   = blksum + 1024;

    hipMemsetAsync(deg, 0, (size_t)N * sizeof(int), stream);

    {   // xn
        int total = N * 35;
        xn_kernel<<<(total + THREADS - 1) / THREADS, THREADS, 0, stream>>>(x, xn, total);
    }
    hist_kernel<<<(E + THREADS - 1) / THREADS, THREADS, 0, stream>>>(edge_index, deg, E);

    int nblk = (N + 2047) / 2048;
    scan1_kernel<<<nblk, THREADS, 0, stream>>>(deg, cursor, blksum, N);
    scan2_kernel<<<1, 1024, 0, stream>>>(blksum, nblk);
    scan3_kernel<<<(N + THREADS - 1) / THREADS, THREADS, 0, stream>>>(cursor, blksum, N);

    scatter_kernel<<<(E + THREADS - 1) / THREADS, THREADS, 0, stream>>>(
        edge_index, cursor, ssrc, E);

    {   // spatial encoder + gather-mean, one wave per node
        int blocks = (N + (THREADS / 64) - 1) / (THREADS / 64);
        spatial_gather_kernel<<<blocks, THREADS, 0, stream>>>(
            pos, deg, cursor, ssrc, sp_w1, sp_b1, sp_ln_g, sp_ln_b, sp_w2, sp_b2,
            pos_emb, N);
    }
    {   // edge processor: one wave per edge
        long long waves = E;
        long long blocks = (waves * 64 + THREADS - 1) / THREADS;
        edgeproc_kernel<<<(int)blocks, THREADS, 0, stream>>>(
            edge_attr, edge_type, e_w, e_b, e_ln_g, e_ln_b, ef, E);
    }
}